// Round 7
// baseline (456.769 us; speedup 1.0000x reference)
//
#include <hip/hip_runtime.h>

#define TSEQ 4096
#define CEMB 768
#define NHEAD 12

using bf16x8 = __attribute__((ext_vector_type(8))) short;
using f32x4  = __attribute__((ext_vector_type(4))) float;

#if __has_builtin(__builtin_amdgcn_exp2f)
#define EXP2(x) __builtin_amdgcn_exp2f(x)
#else
#define EXP2(x) exp2f(x)
#endif

__device__ __forceinline__ unsigned int f2bf(float f) {
    unsigned int u = __float_as_uint(f);
    return (u + 0x7fffu + ((u >> 16) & 1u)) >> 16;   // RNE
}
__device__ __forceinline__ unsigned int f2bf_fast(float f) {
    return (__float_as_uint(f) + 0x8000u) >> 16;     // ~RNE, <=1ulp diff
}
__device__ __forceinline__ void async_cp16(void* lds, const void* g) {
    __builtin_amdgcn_global_load_lds(
        (const __attribute__((address_space(1))) void*)g,
        (__attribute__((address_space(3))) void*)lds, 16, 0, 0);
}
__device__ __forceinline__ float warp_max16(float v) {
    v = fmaxf(v, __shfl_xor(v, 1));
    v = fmaxf(v, __shfl_xor(v, 2));
    v = fmaxf(v, __shfl_xor(v, 4));
    v = fmaxf(v, __shfl_xor(v, 8));
    return v;
}
__device__ __forceinline__ float warp_sum16(float v) {
    v += __shfl_xor(v, 1);
    v += __shfl_xor(v, 2);
    v += __shfl_xor(v, 4);
    v += __shfl_xor(v, 8);
    return v;
}

// ---------------- x fp32 -> bf16 ----------------
__global__ __launch_bounds__(256) void cvt_bf16(
    const float* __restrict__ X, unsigned short* __restrict__ Xb, int n8)
{
    int i = blockIdx.x * 256 + threadIdx.x;
    if (i >= n8) return;
    float4 a = *reinterpret_cast<const float4*>(&X[(size_t)i * 8]);
    float4 b = *reinterpret_cast<const float4*>(&X[(size_t)i * 8 + 4]);
    uint4 o;
    o.x = f2bf(a.x) | (f2bf(a.y) << 16);
    o.y = f2bf(a.z) | (f2bf(a.w) << 16);
    o.z = f2bf(b.x) | (f2bf(b.y) << 16);
    o.w = f2bf(b.z) | (f2bf(b.w) << 16);
    *reinterpret_cast<uint4*>(&Xb[(size_t)i * 8]) = o;
}

// ---------------- W fp32 [K][N] -> bf16 [N][K] ----------------
__global__ __launch_bounds__(256) void wtrans(
    const float* __restrict__ W, unsigned short* __restrict__ WT, int K, int N)
{
    __shared__ unsigned short tile[64][72];
    const int k0 = blockIdx.y * 64, n0 = blockIdx.x * 64;
    const int tid = threadIdx.x;
#pragma unroll
    for (int it = 0; it < 4; ++it) {
        int f = tid + it * 256;
        int r = f >> 4, c4 = f & 15;
        float4 v = *reinterpret_cast<const float4*>(&W[(size_t)(k0 + r) * N + n0 + c4 * 4]);
        tile[r][c4 * 4 + 0] = (unsigned short)f2bf(v.x);
        tile[r][c4 * 4 + 1] = (unsigned short)f2bf(v.y);
        tile[r][c4 * 4 + 2] = (unsigned short)f2bf(v.z);
        tile[r][c4 * 4 + 3] = (unsigned short)f2bf(v.w);
    }
    __syncthreads();
#pragma unroll
    for (int it = 0; it < 2; ++it) {
        int f = tid + it * 256;
        int rn = f >> 3, c8 = f & 7;
        unsigned short tmp[8];
#pragma unroll
        for (int j = 0; j < 8; ++j) tmp[j] = tile[c8 * 8 + j][rn];
        *reinterpret_cast<uint4*>(&WT[(size_t)(n0 + rn) * K + k0 + c8 * 8]) =
            *reinterpret_cast<uint4*>(tmp);
    }
}

// ---------------- bf16 MFMA GEMM: C[m][n] = A[m][k] * BT[n][k] + bias ----------------
template<int BF16OUT, int QSCALE>
__global__ __launch_bounds__(256) void gemm_mfma(
    const unsigned short* __restrict__ A,
    const unsigned short* __restrict__ BT,
    const float* __restrict__ bias,
    void* __restrict__ Cv,
    int M, int N, int K)
{
    __shared__ __align__(16) unsigned short As[128 * 64];
    __shared__ __align__(16) unsigned short Bs[128 * 64];

    const int nwg = gridDim.x * gridDim.y;
    const int id = blockIdx.y * gridDim.x + blockIdx.x;
    const int qx = nwg >> 3;
    const int swz = (id & 7) * qx + (id >> 3);
    const int nb = N >> 7;
    const int m0 = (swz / nb) * 128, n0 = (swz % nb) * 128;

    const int tid = threadIdx.x;
    const int w = tid >> 6, lane = tid & 63;
    const int wr = w >> 1, wc = w & 1;
    const int lq = lane & 15, g = lane >> 4;
    const int wrOff = wr * 64, wcOff = wc * 64;

    f32x4 acc[4][4];
#pragma unroll
    for (int i = 0; i < 4; ++i)
#pragma unroll
        for (int j = 0; j < 4; ++j) acc[i][j] = (f32x4){0.f, 0.f, 0.f, 0.f};

    for (int k0 = 0; k0 < K; k0 += 64) {
#pragma unroll
        for (int it = 0; it < 4; ++it) {
            const int dbase = it * 256 + w * 64;
            const int d = dbase + lane;
            const int r = d >> 3;
            const int s = (d & 7) ^ (r & 7);
            async_cp16((char*)As + dbase * 16, A + (size_t)(m0 + r) * K + k0 + s * 8);
            async_cp16((char*)Bs + dbase * 16, BT + (size_t)(n0 + r) * K + k0 + s * 8);
        }
        __syncthreads();

#pragma unroll
        for (int kk = 0; kk < 2; ++kk) {
            bf16x8 af[4], bfr[4];
#pragma unroll
            for (int i = 0; i < 4; ++i) {
                const int ra = wrOff + i * 16 + lq;
                af[i] = *reinterpret_cast<const bf16x8*>(
                    (char*)As + ra * 128 + (((kk * 4 + g) ^ (ra & 7)) << 4));
                const int rb = wcOff + i * 16 + lq;
                bfr[i] = *reinterpret_cast<const bf16x8*>(
                    (char*)Bs + rb * 128 + (((kk * 4 + g) ^ (rb & 7)) << 4));
            }
#pragma unroll
            for (int i = 0; i < 4; ++i)
#pragma unroll
                for (int j = 0; j < 4; ++j)
                    acc[i][j] = __builtin_amdgcn_mfma_f32_16x16x32_bf16(
                        af[i], bfr[j], acc[i][j], 0, 0, 0);
        }
        __syncthreads();
    }

#pragma unroll
    for (int i = 0; i < 4; ++i)
#pragma unroll
        for (int j = 0; j < 4; ++j) {
            const int col = n0 + wcOff + j * 16 + lq;
            const float bv = bias[col];
            // q gets 1/8 (attn scale) * log2(e) (exp2-domain softmax) folded in
            const float scl = (QSCALE && col < CEMB) ? 0.18033688011112042f : 1.0f;
#pragma unroll
            for (int rg = 0; rg < 4; ++rg) {
                const int row = m0 + wrOff + i * 16 + g * 4 + rg;
                const float v = (acc[i][j][rg] + bv) * scl;
                if (BF16OUT)
                    ((unsigned short*)Cv)[(size_t)row * N + col] = (unsigned short)f2bf(v);
                else
                    ((float*)Cv)[(size_t)row * N + col] = v;
            }
        }
}

// ---------------- V transpose: qkv bf16 v-slice -> Vt [bh][64 d][4096 t] ----------------
__global__ __launch_bounds__(256) void vtrans(
    const unsigned short* __restrict__ qkvB, unsigned short* __restrict__ VtG)
{
    __shared__ unsigned short tile[64][66];
    const int t0 = blockIdx.x * 64;
    const int bh = blockIdx.y;
    const int b = bh / NHEAD, h = bh % NHEAD;
    const size_t rowBase = (size_t)b * TSEQ;
    const int tid = threadIdx.x;

#pragma unroll
    for (int it = 0; it < 2; ++it) {
        int f = tid + 256 * it;
        int r = f >> 3, s = f & 7;
        unsigned short tmp[8];
        *reinterpret_cast<uint4*>(tmp) = *reinterpret_cast<const uint4*>(
            &qkvB[(rowBase + t0 + r) * 2304 + 2 * CEMB + h * 64 + s * 8]);
#pragma unroll
        for (int j = 0; j < 8; ++j) tile[r][s * 8 + j] = tmp[j];
    }
    __syncthreads();
#pragma unroll
    for (int it = 0; it < 2; ++it) {
        int f = tid + 256 * it;
        int d = f >> 3, c = f & 7;
        unsigned short tmp[8];
#pragma unroll
        for (int j = 0; j < 8; ++j) tmp[j] = tile[c * 8 + j][d];
        *reinterpret_cast<uint4*>(&VtG[(size_t)bh * 64 * TSEQ + (size_t)d * TSEQ + t0 + c * 8]) =
            *reinterpret_cast<uint4*>(tmp);
    }
}

// ---- per-tile pieces (layouts identical to the numerically-verified r3/r6 kernel) ----
#define QK_TILE(SFR, QF)                                                              \
{                                                                                     \
    _Pragma("unroll")                                                                 \
    for (int c = 0; c < 4; ++c) {                                                     \
        const int kvr = 16 * c + lq;                                                  \
        const int xr = lq & 7;                                                        \
        bf16x8 k0 = *reinterpret_cast<const bf16x8*>(Kb + kvr * 128 + ((g ^ xr) << 4));       \
        bf16x8 k1 = *reinterpret_cast<const bf16x8*>(Kb + kvr * 128 + (((4 + g) ^ xr) << 4)); \
        f32x4 a0 = (f32x4){0.f, 0.f, 0.f, 0.f};                                       \
        a0 = __builtin_amdgcn_mfma_f32_16x16x32_bf16(QF[0], k0, a0, 0, 0, 0);         \
        a0 = __builtin_amdgcn_mfma_f32_16x16x32_bf16(QF[1], k1, a0, 0, 0, 0);         \
        SFR[c] = a0;                                                                  \
    }                                                                                 \
}

#define MASK_TILE(SFR)                                                                \
{                                                                                     \
    const int qp = 16 * w + 4 * g;                                                    \
    _Pragma("unroll")                                                                 \
    for (int c = 0; c < 4; ++c) {                                                     \
        const int kp = 16 * c + lq;                                                   \
        _Pragma("unroll")                                                             \
        for (int r = 0; r < 4; ++r)                                                   \
            if (kp > qp + r) SFR[c][r] = -1e30f;                                      \
    }                                                                                 \
}

// online softmax with defer-rescale (T13): THR = 8 nats = 11.5 in exp2 domain
#define SM_TILE(SFR, MM, LL, OO)                                                      \
{                                                                                     \
    float mxv[4];                                                                     \
    _Pragma("unroll")                                                                 \
    for (int r = 0; r < 4; ++r) {                                                     \
        float mx = fmaxf(fmaxf(SFR[0][r], SFR[1][r]), fmaxf(SFR[2][r], SFR[3][r]));   \
        mxv[r] = warp_max16(mx);                                                      \
    }                                                                                 \
    bool big = false;                                                                 \
    _Pragma("unroll")                                                                 \
    for (int r = 0; r < 4; ++r) big = big || (mxv[r] > MM[r] + 11.5f);                \
    if (__any(big)) {                                                                 \
        _Pragma("unroll")                                                             \
        for (int r = 0; r < 4; ++r) {                                                 \
            const float mnew = fmaxf(MM[r], mxv[r]);                                  \
            const float al = EXP2(MM[r] - mnew);                                      \
            float rs = 0.f;                                                           \
            _Pragma("unroll")                                                         \
            for (int c = 0; c < 4; ++c) {                                             \
                const float p = EXP2(SFR[c][r] - mnew);                               \
                SFR[c][r] = p;                                                        \
                rs += p;                                                              \
            }                                                                         \
            rs = warp_sum16(rs);                                                      \
            LL[r] = al * LL[r] + rs;                                                  \
            MM[r] = mnew;                                                             \
            _Pragma("unroll")                                                         \
            for (int dt = 0; dt < 4; ++dt) OO[dt][r] *= al;                           \
        }                                                                             \
    } else {                                                                          \
        _Pragma("unroll")                                                             \
        for (int r = 0; r < 4; ++r) {                                                 \
            float rs = 0.f;                                                           \
            _Pragma("unroll")                                                         \
            for (int c = 0; c < 4; ++c) {                                             \
                const float p = EXP2(SFR[c][r] - MM[r]);                              \
                SFR[c][r] = p;                                                        \
                rs += p;                                                              \
            }                                                                         \
            rs = warp_sum16(rs);                                                      \
            LL[r] += rs;                                                              \
        }                                                                             \
    }                                                                                 \
}

#define PW_TILE(SFR, PWP)                                                             \
{                                                                                     \
    _Pragma("unroll")                                                                 \
    for (int c = 0; c < 4; ++c) {                                                     \
        const int kp = 16 * c + lq;                                                   \
        _Pragma("unroll")                                                             \
        for (int r = 0; r < 4; ++r) {                                                 \
            const int qp = 4 * g + r;                                                 \
            const int byt = qp * 128 + (((kp >> 3) ^ (qp & 7)) << 4) + (kp & 7) * 2;  \
            *reinterpret_cast<unsigned short*>(PWP + byt) =                           \
                (unsigned short)f2bf_fast(SFR[c][r]);                                 \
        }                                                                             \
    }                                                                                 \
}

#define PV_TILE(OO, PWP)                                                              \
{                                                                                     \
    _Pragma("unroll")                                                                 \
    for (int ktile = 0; ktile < 2; ++ktile) {                                         \
        bf16x8 pf = *reinterpret_cast<const bf16x8*>(                                 \
            PWP + lq * 128 + (((4 * ktile + g) ^ (lq & 7)) << 4));                    \
        _Pragma("unroll")                                                             \
        for (int dt = 0; dt < 4; ++dt) {                                              \
            const int d = 16 * dt + lq;                                               \
            bf16x8 vf = *reinterpret_cast<const bf16x8*>(                             \
                Vb + d * 128 + (((4 * ktile + g) ^ (d & 7)) << 4));                   \
            OO[dt] = __builtin_amdgcn_mfma_f32_16x16x32_bf16(pf, vf, OO[dt], 0, 0, 0);\
        }                                                                             \
    }                                                                                 \
}

#define STAGE_KV(KT, BUF)                                                             \
{                                                                                     \
    const int kn = (KT) * 64;                                                         \
    _Pragma("unroll")                                                                 \
    for (int it = 0; it < 2; ++it) {                                                  \
        const int dbase = it * 256 + w * 64;                                          \
        const int d = dbase + lane;                                                   \
        const int r = d >> 3;                                                         \
        const int s = (d & 7) ^ (r & 7);                                              \
        async_cp16(Kl[BUF] + dbase * 16, qkvB + (rowBase + kn + r) * 2304 + kOff + s * 8); \
        async_cp16(Vl[BUF] + dbase * 16, Vhead + (size_t)r * TSEQ + kn + s * 8);      \
    }                                                                                 \
}

#define PAIR(SA, SB, QA, QB, MA, LA, OA, MB, LB, OB, PA, PB, DIAGA)                   \
{                                                                                     \
    QK_TILE(SA, QA); QK_TILE(SB, QB);                                                 \
    if (DIAGA) MASK_TILE(SA);                                                         \
    SM_TILE(SA, MA, LA, OA); SM_TILE(SB, MB, LB, OB);                                 \
    PW_TILE(SA, PA); PW_TILE(SB, PB);                                                 \
    PV_TILE(OA, PA); PV_TILE(OB, PB);                                                 \
}

#define SINGLE(SA, QA, MA, LA, OA, PA, DIAGA)                                         \
{                                                                                     \
    QK_TILE(SA, QA);                                                                  \
    if (DIAGA) MASK_TILE(SA);                                                         \
    SM_TILE(SA, MA, LA, OA);                                                          \
    PW_TILE(SA, PA);                                                                  \
    PV_TILE(OA, PA);                                                                  \
}

// ---------------- MFMA flash attention v5: 4 contiguous q-tiles/block, XCD-local bh ----------------
// 1-D grid of 384 blocks. XCD k (id&7) gets bh = 3k..3k+2, sizes a=15..0 heavy-first.
__global__ __launch_bounds__(256, 2) void attn_mfma5(
    const unsigned short* __restrict__ qkvB,   // bf16 [8192][2304], q pre-scaled 0.125*log2e
    const unsigned short* __restrict__ VtG,    // bf16 [24][64][4096]
    unsigned short* __restrict__ Yb)           // bf16 [8192][768]
{
    __shared__ __align__(16) char Kl[2][8192];   // [kv 64][d 64], 16B-chunk XOR swizzle
    __shared__ __align__(16) char Vl[2][8192];   // [d 64][kv 64], swizzled
    __shared__ __align__(16) char Pl[32768];     // 4 waves x 4 chains x [q16][kv64]

    const int id = blockIdx.x;                   // 0..383
    const int L = (id & 7) * 48 + (id >> 3);     // XCD-contiguous logical index
    const int bh = L >> 4;                       // 0..23 (3 bh per XCD)
    const int a = 15 - (L & 15);                 // heavy-first within XCD
    const int qt0 = a * 4;                       // tiles qt0..qt0+3

    const int b = bh / NHEAD, h = bh % NHEAD;
    const int tid = threadIdx.x;
    const int w = tid >> 6, lane = tid & 63;
    const int g = lane >> 4, lq = lane & 15;

    const size_t rowBase = (size_t)b * TSEQ;
    const int kOff = CEMB + h * 64;
    const unsigned short* Vhead = VtG + (size_t)bh * 64 * TSEQ;

    // Q fragments, acc state x4 tiles
    bf16x8 qf0[2], qf1[2], qf2[2], qf3[2];
    {
        const size_t r0 = rowBase + (size_t)(qt0 + 0) * 64 + 16 * w + lq;
        const size_t r1 = rowBase + (size_t)(qt0 + 1) * 64 + 16 * w + lq;
        const size_t r2 = rowBase + (size_t)(qt0 + 2) * 64 + 16 * w + lq;
        const size_t r3 = rowBase + (size_t)(qt0 + 3) * 64 + 16 * w + lq;
#pragma unroll
        for (int dt = 0; dt < 2; ++dt) {
            qf0[dt] = *reinterpret_cast<const bf16x8*>(&qkvB[r0 * 2304 + h * 64 + 32 * dt + 8 * g]);
            qf1[dt] = *reinterpret_cast<const bf16x8*>(&qkvB[r1 * 2304 + h * 64 + 32 * dt + 8 * g]);
            qf2[dt] = *reinterpret_cast<const bf16x8*>(&qkvB[r2 * 2304 + h * 64 + 32 * dt + 8 * g]);
            qf3[dt] = *reinterpret_cast<const bf16x8*>(&qkvB[r3 * 2304 + h * 64 + 32 * dt + 8 * g]);
        }
    }

    f32x4 o0[4], o1[4], o2[4], o3[4];
    float m0[4], l0[4], m1[4], l1[4], m2[4], l2[4], m3[4], l3[4];
#pragma unroll
    for (int r = 0; r < 4; ++r) {
        m0[r] = m1[r] = m2[r] = m3[r] = -1e30f;
        l0[r] = l1[r] = l2[r] = l3[r] = 0.f;
    }
#pragma unroll
    for (int dt = 0; dt < 4; ++dt) {
        o0[dt] = (f32x4){0.f, 0.f, 0.f, 0.f};
        o1[dt] = (f32x4){0.f, 0.f, 0.f, 0.f};
        o2[dt] = (f32x4){0.f, 0.f, 0.f, 0.f};
        o3[dt] = (f32x4){0.f, 0.f, 0.f, 0.f};
    }

    char* Pw0 = Pl + (w * 4 + 0) * 2048;
    char* Pw1 = Pl + (w * 4 + 1) * 2048;
    char* Pw2 = Pl + (w * 4 + 2) * 2048;
    char* Pw3 = Pl + (w * 4 + 3) * 2048;

    STAGE_KV(0, 0);

    int kt = 0;
    // main: all 4 chains active
    for (; kt <= qt0; ++kt) {
        const int cur = kt & 1;
        __syncthreads();
        STAGE_KV(kt + 1, cur ^ 1);               // kt+1 <= qt0+1 <= qt0+3, valid
        const char* Kb = Kl[cur];
        const char* Vb = Vl[cur];
        f32x4 sA[4], sB[4];
        PAIR(sA, sB, qf0, qf1, m0, l0, o0, m1, l1, o1, Pw0, Pw1, (kt == qt0));
        PAIR(sA, sB, qf2, qf3, m2, l2, o2, m3, l3, o3, Pw2, Pw3, false);
    }
    // tail 1: tiles 1(diag),2,3
    {
        const int cur = kt & 1;
        __syncthreads();
        STAGE_KV(kt + 1, cur ^ 1);
        const char* Kb = Kl[cur];
        const char* Vb = Vl[cur];
        f32x4 sA[4], sB[4];
        PAIR(sA, sB, qf1, qf2, m1, l1, o1, m2, l2, o2, Pw1, Pw2, true);
        SINGLE(sA, qf3, m3, l3, o3, Pw3, false);
        ++kt;
    }
    // tail 2: tiles 2(diag),3
    {
        const int cur = kt & 1;
        __syncthreads();
        STAGE_KV(kt + 1, cur ^ 1);
        const char* Kb = Kl[cur];
        const char* Vb = Vl[cur];
        f32x4 sA[4], sB[4];
        PAIR(sA, sB, qf2, qf3, m2, l2, o2, m3, l3, o3, Pw2, Pw3, true);
        ++kt;
    }
    // tail 3: tile 3(diag)
    {
        const int cur = kt & 1;
        __syncthreads();
        const char* Kb = Kl[cur];
        const char* Vb = Vl[cur];
        f32x4 sA[4];
        SINGLE(sA, qf3, m3, l3, o3, Pw3, true);
    }

    // ---- outputs: 4 tiles ----
#pragma unroll
    for (int r = 0; r < 4; ++r) {
        const float i0 = 1.f / l0[r], i1 = 1.f / l1[r];
        const float i2 = 1.f / l2[r], i3 = 1.f / l3[r];
        const size_t r0 = rowBase + (size_t)(qt0 + 0) * 64 + 16 * w + 4 * g + r;
        const size_t r1 = rowBase + (size_t)(qt0 + 1) * 64 + 16 * w + 4 * g + r;
        const size_t r2 = rowBase + (size_t)(qt0 + 2) * 64 + 16 * w + 4 * g + r;
        const size_t r3 = rowBase + (size_t)(qt0 + 3) * 64 + 16 * w + 4 * g + r;
#pragma unroll
        for (int dt = 0; dt < 4; ++dt) {
            Yb[r0 * CEMB + h * 64 + 16 * dt + lq] = (unsigned short)f2bf_fast(o0[dt][r] * i0);
            Yb[r1 * CEMB + h * 64 + 16 * dt + lq] = (unsigned short)f2bf_fast(o1[dt][r] * i1);
            Yb[r2 * CEMB + h * 64 + 16 * dt + lq] = (unsigned short)f2bf_fast(o2[dt][r] * i2);
            Yb[r3 * CEMB + h * 64 + 16 * dt + lq] = (unsigned short)f2bf_fast(o3[dt][r] * i3);
        }
    }
}

extern "C" void kernel_launch(void* const* d_in, const int* in_sizes, int n_in,
                              void* d_out, int out_size, void* d_ws, size_t ws_size,
                              hipStream_t stream)
{
    const float* x      = (const float*)d_in[0];
    const float* w_attn = (const float*)d_in[1];
    const float* b_attn = (const float*)d_in[2];
    const float* w_proj = (const float*)d_in[3];
    const float* b_proj = (const float*)d_in[4];
    float* out = (float*)d_out;

    const int M = 2 * TSEQ;  // 8192
    char* ws = (char*)d_ws;
    unsigned short* qkvB = (unsigned short*)ws;                   // 37,748,736 B
    unsigned short* VtG  = (unsigned short*)(ws + 37748736);      // 12,582,912 B
    unsigned short* xYb  = (unsigned short*)(ws + 50331648);      // 12,582,912 B (xB, then Yb)
    unsigned short* wT   = (unsigned short*)(ws + 62914560);      //  3,538,944 B
    unsigned short* wpT  = (unsigned short*)(ws + 66453504);      //  1,179,648 B

    cvt_bf16<<<dim3((M * CEMB) / 8 / 256), 256, 0, stream>>>(x, xYb, (M * CEMB) / 8);
    wtrans<<<dim3(3 * CEMB / 64, CEMB / 64), 256, 0, stream>>>(w_attn, wT, CEMB, 3 * CEMB);
    wtrans<<<dim3(CEMB / 64, CEMB / 64), 256, 0, stream>>>(w_proj, wpT, CEMB, CEMB);

    gemm_mfma<1, 1><<<dim3(3 * CEMB / 128, M / 128), 256, 0, stream>>>(
        xYb, wT, b_attn, qkvB, M, 3 * CEMB, CEMB);

    vtrans<<<dim3(TSEQ / 64, 2 * NHEAD), 256, 0, stream>>>(qkvB, VtG);

    attn_mfma5<<<dim3(384), 256, 0, stream>>>(qkvB, VtG, xYb);

    gemm_mfma<0, 0><<<dim3(CEMB / 128, M / 128), 256, 0, stream>>>(
        xYb, wpT, b_proj, out, M, CEMB, CEMB);
}

// Round 8
// 385.451 us; speedup vs baseline: 1.1850x; 1.1850x over previous
//
#include <hip/hip_runtime.h>

#define TSEQ 4096
#define CEMB 768
#define NHEAD 12

using bf16x8 = __attribute__((ext_vector_type(8))) short;
using f32x4  = __attribute__((ext_vector_type(4))) float;

#if __has_builtin(__builtin_amdgcn_exp2f)
#define EXP2(x) __builtin_amdgcn_exp2f(x)
#else
#define EXP2(x) exp2f(x)
#endif

__device__ __forceinline__ unsigned int f2bf(float f) {
    unsigned int u = __float_as_uint(f);
    return (u + 0x7fffu + ((u >> 16) & 1u)) >> 16;   // RNE
}
__device__ __forceinline__ unsigned int f2bf_fast(float f) {
    return (__float_as_uint(f) + 0x8000u) >> 16;     // ~RNE, <=1ulp diff
}
__device__ __forceinline__ void async_cp16(void* lds, const void* g) {
    __builtin_amdgcn_global_load_lds(
        (const __attribute__((address_space(1))) void*)g,
        (__attribute__((address_space(3))) void*)lds, 16, 0, 0);
}
__device__ __forceinline__ float warp_max16(float v) {
    v = fmaxf(v, __shfl_xor(v, 1));
    v = fmaxf(v, __shfl_xor(v, 2));
    v = fmaxf(v, __shfl_xor(v, 4));
    v = fmaxf(v, __shfl_xor(v, 8));
    return v;
}
__device__ __forceinline__ float warp_sum16(float v) {
    v += __shfl_xor(v, 1);
    v += __shfl_xor(v, 2);
    v += __shfl_xor(v, 4);
    v += __shfl_xor(v, 8);
    return v;
}

// ---------------- x fp32 -> bf16 ----------------
__global__ __launch_bounds__(256) void cvt_bf16(
    const float* __restrict__ X, unsigned short* __restrict__ Xb, int n8)
{
    int i = blockIdx.x * 256 + threadIdx.x;
    if (i >= n8) return;
    float4 a = *reinterpret_cast<const float4*>(&X[(size_t)i * 8]);
    float4 b = *reinterpret_cast<const float4*>(&X[(size_t)i * 8 + 4]);
    uint4 o;
    o.x = f2bf(a.x) | (f2bf(a.y) << 16);
    o.y = f2bf(a.z) | (f2bf(a.w) << 16);
    o.z = f2bf(b.x) | (f2bf(b.y) << 16);
    o.w = f2bf(b.z) | (f2bf(b.w) << 16);
    *reinterpret_cast<uint4*>(&Xb[(size_t)i * 8]) = o;
}

// ---------------- W fp32 [K][N] -> bf16 [N][K] ----------------
__global__ __launch_bounds__(256) void wtrans(
    const float* __restrict__ W, unsigned short* __restrict__ WT, int K, int N)
{
    __shared__ unsigned short tile[64][72];
    const int k0 = blockIdx.y * 64, n0 = blockIdx.x * 64;
    const int tid = threadIdx.x;
#pragma unroll
    for (int it = 0; it < 4; ++it) {
        int f = tid + it * 256;
        int r = f >> 4, c4 = f & 15;
        float4 v = *reinterpret_cast<const float4*>(&W[(size_t)(k0 + r) * N + n0 + c4 * 4]);
        tile[r][c4 * 4 + 0] = (unsigned short)f2bf(v.x);
        tile[r][c4 * 4 + 1] = (unsigned short)f2bf(v.y);
        tile[r][c4 * 4 + 2] = (unsigned short)f2bf(v.z);
        tile[r][c4 * 4 + 3] = (unsigned short)f2bf(v.w);
    }
    __syncthreads();
#pragma unroll
    for (int it = 0; it < 2; ++it) {
        int f = tid + it * 256;
        int rn = f >> 3, c8 = f & 7;
        unsigned short tmp[8];
#pragma unroll
        for (int j = 0; j < 8; ++j) tmp[j] = tile[c8 * 8 + j][rn];
        *reinterpret_cast<uint4*>(&WT[(size_t)(n0 + rn) * K + k0 + c8 * 8]) =
            *reinterpret_cast<uint4*>(tmp);
    }
}

// ---------------- bf16 MFMA GEMM: C[m][n] = A[m][k] * BT[n][k] + bias ----------------
template<int BF16OUT, int QSCALE>
__global__ __launch_bounds__(256) void gemm_mfma(
    const unsigned short* __restrict__ A,
    const unsigned short* __restrict__ BT,
    const float* __restrict__ bias,
    void* __restrict__ Cv,
    int M, int N, int K)
{
    __shared__ __align__(16) unsigned short As[128 * 64];
    __shared__ __align__(16) unsigned short Bs[128 * 64];

    const int nwg = gridDim.x * gridDim.y;
    const int id = blockIdx.y * gridDim.x + blockIdx.x;
    const int qx = nwg >> 3;
    const int swz = (id & 7) * qx + (id >> 3);
    const int nb = N >> 7;
    const int m0 = (swz / nb) * 128, n0 = (swz % nb) * 128;

    const int tid = threadIdx.x;
    const int w = tid >> 6, lane = tid & 63;
    const int wr = w >> 1, wc = w & 1;
    const int lq = lane & 15, g = lane >> 4;
    const int wrOff = wr * 64, wcOff = wc * 64;

    f32x4 acc[4][4];
#pragma unroll
    for (int i = 0; i < 4; ++i)
#pragma unroll
        for (int j = 0; j < 4; ++j) acc[i][j] = (f32x4){0.f, 0.f, 0.f, 0.f};

    for (int k0 = 0; k0 < K; k0 += 64) {
#pragma unroll
        for (int it = 0; it < 4; ++it) {
            const int dbase = it * 256 + w * 64;
            const int d = dbase + lane;
            const int r = d >> 3;
            const int s = (d & 7) ^ (r & 7);
            async_cp16((char*)As + dbase * 16, A + (size_t)(m0 + r) * K + k0 + s * 8);
            async_cp16((char*)Bs + dbase * 16, BT + (size_t)(n0 + r) * K + k0 + s * 8);
        }
        __syncthreads();

#pragma unroll
        for (int kk = 0; kk < 2; ++kk) {
            bf16x8 af[4], bfr[4];
#pragma unroll
            for (int i = 0; i < 4; ++i) {
                const int ra = wrOff + i * 16 + lq;
                af[i] = *reinterpret_cast<const bf16x8*>(
                    (char*)As + ra * 128 + (((kk * 4 + g) ^ (ra & 7)) << 4));
                const int rb = wcOff + i * 16 + lq;
                bfr[i] = *reinterpret_cast<const bf16x8*>(
                    (char*)Bs + rb * 128 + (((kk * 4 + g) ^ (rb & 7)) << 4));
            }
#pragma unroll
            for (int i = 0; i < 4; ++i)
#pragma unroll
                for (int j = 0; j < 4; ++j)
                    acc[i][j] = __builtin_amdgcn_mfma_f32_16x16x32_bf16(
                        af[i], bfr[j], acc[i][j], 0, 0, 0);
        }
        __syncthreads();
    }

#pragma unroll
    for (int i = 0; i < 4; ++i)
#pragma unroll
        for (int j = 0; j < 4; ++j) {
            const int col = n0 + wcOff + j * 16 + lq;
            const float bv = bias[col];
            // q gets 1/8 (attn scale) * log2(e) (exp2-domain softmax) folded in
            const float scl = (QSCALE && col < CEMB) ? 0.18033688011112042f : 1.0f;
#pragma unroll
            for (int rg = 0; rg < 4; ++rg) {
                const int row = m0 + wrOff + i * 16 + g * 4 + rg;
                const float v = (acc[i][j][rg] + bv) * scl;
                if (BF16OUT)
                    ((unsigned short*)Cv)[(size_t)row * N + col] = (unsigned short)f2bf(v);
                else
                    ((float*)Cv)[(size_t)row * N + col] = v;
            }
        }
}

// ---------------- V transpose: qkv bf16 v-slice -> Vt [bh][64 d][4096 t] ----------------
__global__ __launch_bounds__(256) void vtrans(
    const unsigned short* __restrict__ qkvB, unsigned short* __restrict__ VtG)
{
    __shared__ unsigned short tile[64][66];
    const int t0 = blockIdx.x * 64;
    const int bh = blockIdx.y;
    const int b = bh / NHEAD, h = bh % NHEAD;
    const size_t rowBase = (size_t)b * TSEQ;
    const int tid = threadIdx.x;

#pragma unroll
    for (int it = 0; it < 2; ++it) {
        int f = tid + 256 * it;
        int r = f >> 3, s = f & 7;
        unsigned short tmp[8];
        *reinterpret_cast<uint4*>(tmp) = *reinterpret_cast<const uint4*>(
            &qkvB[(rowBase + t0 + r) * 2304 + 2 * CEMB + h * 64 + s * 8]);
#pragma unroll
        for (int j = 0; j < 8; ++j) tile[r][s * 8 + j] = tmp[j];
    }
    __syncthreads();
#pragma unroll
    for (int it = 0; it < 2; ++it) {
        int f = tid + 256 * it;
        int d = f >> 3, c = f & 7;
        unsigned short tmp[8];
#pragma unroll
        for (int j = 0; j < 8; ++j) tmp[j] = tile[c * 8 + j][d];
        *reinterpret_cast<uint4*>(&VtG[(size_t)bh * 64 * TSEQ + (size_t)d * TSEQ + t0 + c * 8]) =
            *reinterpret_cast<uint4*>(tmp);
    }
}

// ---- per-tile pieces (layouts identical to the numerically-verified r3/r6 kernel) ----
#define QK_TILE(SFR, QF)                                                              \
{                                                                                     \
    _Pragma("unroll")                                                                 \
    for (int c = 0; c < 4; ++c) {                                                     \
        const int kvr = 16 * c + lq;                                                  \
        const int xr = lq & 7;                                                        \
        bf16x8 k0 = *reinterpret_cast<const bf16x8*>(Kb + kvr * 128 + ((g ^ xr) << 4));       \
        bf16x8 k1 = *reinterpret_cast<const bf16x8*>(Kb + kvr * 128 + (((4 + g) ^ xr) << 4)); \
        f32x4 a0 = (f32x4){0.f, 0.f, 0.f, 0.f};                                       \
        a0 = __builtin_amdgcn_mfma_f32_16x16x32_bf16(QF[0], k0, a0, 0, 0, 0);         \
        a0 = __builtin_amdgcn_mfma_f32_16x16x32_bf16(QF[1], k1, a0, 0, 0, 0);         \
        SFR[c] = a0;                                                                  \
    }                                                                                 \
}

#define MASK_TILE(SFR)                                                                \
{                                                                                     \
    const int qp = 16 * w + 4 * g;                                                    \
    _Pragma("unroll")                                                                 \
    for (int c = 0; c < 4; ++c) {                                                     \
        const int kp = 16 * c + lq;                                                   \
        _Pragma("unroll")                                                             \
        for (int r = 0; r < 4; ++r)                                                   \
            if (kp > qp + r) SFR[c][r] = -1e30f;                                      \
    }                                                                                 \
}

// online softmax with defer-rescale (T13): THR = 8 nats = 11.5 in exp2 domain
#define SM_TILE(SFR, MM, LL, OO)                                                      \
{                                                                                     \
    float mxv[4];                                                                     \
    _Pragma("unroll")                                                                 \
    for (int r = 0; r < 4; ++r) {                                                     \
        float mx = fmaxf(fmaxf(SFR[0][r], SFR[1][r]), fmaxf(SFR[2][r], SFR[3][r]));   \
        mxv[r] = warp_max16(mx);                                                      \
    }                                                                                 \
    bool big = false;                                                                 \
    _Pragma("unroll")                                                                 \
    for (int r = 0; r < 4; ++r) big = big || (mxv[r] > MM[r] + 11.5f);                \
    if (__any(big)) {                                                                 \
        _Pragma("unroll")                                                             \
        for (int r = 0; r < 4; ++r) {                                                 \
            const float mnew = fmaxf(MM[r], mxv[r]);                                  \
            const float al = EXP2(MM[r] - mnew);                                      \
            float rs = 0.f;                                                           \
            _Pragma("unroll")                                                         \
            for (int c = 0; c < 4; ++c) {                                             \
                const float p = EXP2(SFR[c][r] - mnew);                               \
                SFR[c][r] = p;                                                        \
                rs += p;                                                              \
            }                                                                         \
            rs = warp_sum16(rs);                                                      \
            LL[r] = al * LL[r] + rs;                                                  \
            MM[r] = mnew;                                                             \
            _Pragma("unroll")                                                         \
            for (int dt = 0; dt < 4; ++dt) OO[dt][r] *= al;                           \
        }                                                                             \
    } else {                                                                          \
        _Pragma("unroll")                                                             \
        for (int r = 0; r < 4; ++r) {                                                 \
            float rs = 0.f;                                                           \
            _Pragma("unroll")                                                         \
            for (int c = 0; c < 4; ++c) {                                             \
                const float p = EXP2(SFR[c][r] - MM[r]);                              \
                SFR[c][r] = p;                                                        \
                rs += p;                                                              \
            }                                                                         \
            rs = warp_sum16(rs);                                                      \
            LL[r] += rs;                                                              \
        }                                                                             \
    }                                                                                 \
}

#define PW_TILE(SFR, PWP)                                                             \
{                                                                                     \
    _Pragma("unroll")                                                                 \
    for (int c = 0; c < 4; ++c) {                                                     \
        const int kp = 16 * c + lq;                                                   \
        _Pragma("unroll")                                                             \
        for (int r = 0; r < 4; ++r) {                                                 \
            const int qp = 4 * g + r;                                                 \
            const int byt = qp * 128 + (((kp >> 3) ^ (qp & 7)) << 4) + (kp & 7) * 2;  \
            *reinterpret_cast<unsigned short*>(PWP + byt) =                           \
                (unsigned short)f2bf_fast(SFR[c][r]);                                 \
        }                                                                             \
    }                                                                                 \
}

#define PV_TILE(OO, PWP)                                                              \
{                                                                                     \
    _Pragma("unroll")                                                                 \
    for (int ktile = 0; ktile < 2; ++ktile) {                                         \
        bf16x8 pf = *reinterpret_cast<const bf16x8*>(                                 \
            PWP + lq * 128 + (((4 * ktile + g) ^ (lq & 7)) << 4));                    \
        _Pragma("unroll")                                                             \
        for (int dt = 0; dt < 4; ++dt) {                                              \
            const int d = 16 * dt + lq;                                               \
            bf16x8 vf = *reinterpret_cast<const bf16x8*>(                             \
                Vb + d * 128 + (((4 * ktile + g) ^ (d & 7)) << 4));                   \
            OO[dt] = __builtin_amdgcn_mfma_f32_16x16x32_bf16(pf, vf, OO[dt], 0, 0, 0);\
        }                                                                             \
    }                                                                                 \
}

#define STAGE_KV(KT, BUF)                                                             \
{                                                                                     \
    const int kn = (KT) * 64;                                                         \
    _Pragma("unroll")                                                                 \
    for (int it = 0; it < 2; ++it) {                                                  \
        const int dbase = it * 256 + w * 64;                                          \
        const int d = dbase + lane;                                                   \
        const int r = d >> 3;                                                         \
        const int s = (d & 7) ^ (r & 7);                                              \
        async_cp16(Kl[BUF] + dbase * 16, qkvB + (rowBase + kn + r) * 2304 + kOff + s * 8); \
        async_cp16(Vl[BUF] + dbase * 16, Vhead + (size_t)r * TSEQ + kn + s * 8);      \
    }                                                                                 \
}

// ---------------- MFMA flash attention v6: r6 pair structure + XCD-bijective bh mapping ----------------
// 1-D grid 768. XCD k (= id&7) owns bh = 3k + (local%3); qtA = local/3 pairs with 63-qtA.
__global__ __launch_bounds__(256, 3) void attn_mfma6(
    const unsigned short* __restrict__ qkvB,   // bf16 [8192][2304], q pre-scaled 0.125*log2e
    const unsigned short* __restrict__ VtG,    // bf16 [24][64][4096]
    unsigned short* __restrict__ Yb)           // bf16 [8192][768]
{
    __shared__ __align__(16) char Kl[2][8192];   // [kv 64][d 64], 16B-chunk XOR swizzle
    __shared__ __align__(16) char Vl[2][8192];   // [d 64][kv 64], swizzled
    __shared__ __align__(16) char PlA[8192];     // 4 waves x [q 16][kv 64], swizzled
    __shared__ __align__(16) char PlB[8192];

    const int NT = TSEQ / 64;
    const int id = blockIdx.x;                   // 0..767
    const int xcd = id & 7;
    const int local = id >> 3;                   // 0..95
    const int bh = xcd * 3 + (local % 3);        // 3 bh per XCD -> K/V L2-resident
    const int qtA = local / 3;                   // 0..31
    const int qtB = NT - 1 - qtA;                // 63..32

    const int b = bh / NHEAD, h = bh % NHEAD;
    const int tid = threadIdx.x;
    const int w = tid >> 6, lane = tid & 63;
    const int g = lane >> 4, lq = lane & 15;

    const size_t rowBase = (size_t)b * TSEQ;
    const int kOff = CEMB + h * 64;
    const unsigned short* Vhead = VtG + (size_t)bh * 64 * TSEQ;

    bf16x8 qfA[2], qfB[2];
    {
        const size_t rA = rowBase + (size_t)qtA * 64 + 16 * w + lq;
        const size_t rB = rowBase + (size_t)qtB * 64 + 16 * w + lq;
#pragma unroll
        for (int dt = 0; dt < 2; ++dt) {
            qfA[dt] = *reinterpret_cast<const bf16x8*>(&qkvB[rA * 2304 + h * 64 + 32 * dt + 8 * g]);
            qfB[dt] = *reinterpret_cast<const bf16x8*>(&qkvB[rB * 2304 + h * 64 + 32 * dt + 8 * g]);
        }
    }

    f32x4 oA[4], oB[4];
    float mA[4], lA[4], mB[4], lB[4];
#pragma unroll
    for (int r = 0; r < 4; ++r) {
        mA[r] = -1e30f; lA[r] = 0.f; mB[r] = -1e30f; lB[r] = 0.f;
    }
#pragma unroll
    for (int dt = 0; dt < 4; ++dt) {
        oA[dt] = (f32x4){0.f, 0.f, 0.f, 0.f};
        oB[dt] = (f32x4){0.f, 0.f, 0.f, 0.f};
    }

    char* PwA = PlA + w * 2048;
    char* PwB = PlB + w * 2048;

    STAGE_KV(0, 0);

    // ---- phase 1: kt = 0..qtA — both tiles active, staggered dual chains ----
    for (int kt = 0; kt <= qtA; ++kt) {
        const int cur = kt & 1;
        __syncthreads();
        STAGE_KV(kt + 1, cur ^ 1);           // kt+1 <= qtA+1 <= qtB, always valid
        const char* Kb = Kl[cur];
        const char* Vb = Vl[cur];

        f32x4 sfrA[4], sfrB[4];
        QK_TILE(sfrA, qfA);
        QK_TILE(sfrB, qfB);
        if (kt == qtA) MASK_TILE(sfrA);
        SM_TILE(sfrA, mA, lA, oA);
        SM_TILE(sfrB, mB, lB, oB);
        PW_TILE(sfrA, PwA);
        PW_TILE(sfrB, PwB);
        PV_TILE(oA, PwA);
        PV_TILE(oB, PwB);
    }

    // ---- phase 2: kt = qtA+1..qtB — only tile B ----
    for (int kt = qtA + 1; kt <= qtB; ++kt) {
        const int cur = kt & 1;
        __syncthreads();
        if (kt < qtB) STAGE_KV(kt + 1, cur ^ 1);
        const char* Kb = Kl[cur];
        const char* Vb = Vl[cur];

        f32x4 sfrB[4];
        QK_TILE(sfrB, qfB);
        if (kt == qtB) MASK_TILE(sfrB);
        SM_TILE(sfrB, mB, lB, oB);
        PW_TILE(sfrB, PwB);
        PV_TILE(oB, PwB);
    }

    // ---- outputs ----
#pragma unroll
    for (int r = 0; r < 4; ++r) {
        const float invA = 1.f / lA[r];
        const float invB = 1.f / lB[r];
        const size_t rowA = rowBase + (size_t)qtA * 64 + 16 * w + 4 * g + r;
        const size_t rowB = rowBase + (size_t)qtB * 64 + 16 * w + 4 * g + r;
#pragma unroll
        for (int dt = 0; dt < 4; ++dt) {
            Yb[rowA * CEMB + h * 64 + 16 * dt + lq] = (unsigned short)f2bf_fast(oA[dt][r] * invA);
            Yb[rowB * CEMB + h * 64 + 16 * dt + lq] = (unsigned short)f2bf_fast(oB[dt][r] * invB);
        }
    }
}

extern "C" void kernel_launch(void* const* d_in, const int* in_sizes, int n_in,
                              void* d_out, int out_size, void* d_ws, size_t ws_size,
                              hipStream_t stream)
{
    const float* x      = (const float*)d_in[0];
    const float* w_attn = (const float*)d_in[1];
    const float* b_attn = (const float*)d_in[2];
    const float* w_proj = (const float*)d_in[3];
    const float* b_proj = (const float*)d_in[4];
    float* out = (float*)d_out;

    const int M = 2 * TSEQ;  // 8192
    char* ws = (char*)d_ws;
    unsigned short* qkvB = (unsigned short*)ws;                   // 37,748,736 B
    unsigned short* VtG  = (unsigned short*)(ws + 37748736);      // 12,582,912 B
    unsigned short* xYb  = (unsigned short*)(ws + 50331648);      // 12,582,912 B (xB, then Yb)
    unsigned short* wT   = (unsigned short*)(ws + 62914560);      //  3,538,944 B
    unsigned short* wpT  = (unsigned short*)(ws + 66453504);      //  1,179,648 B

    cvt_bf16<<<dim3((M * CEMB) / 8 / 256), 256, 0, stream>>>(x, xYb, (M * CEMB) / 8);
    wtrans<<<dim3(3 * CEMB / 64, CEMB / 64), 256, 0, stream>>>(w_attn, wT, CEMB, 3 * CEMB);
    wtrans<<<dim3(CEMB / 64, CEMB / 64), 256, 0, stream>>>(w_proj, wpT, CEMB, CEMB);

    gemm_mfma<1, 1><<<dim3(3 * CEMB / 128, M / 128), 256, 0, stream>>>(
        xYb, wT, b_attn, qkvB, M, 3 * CEMB, CEMB);

    vtrans<<<dim3(TSEQ / 64, 2 * NHEAD), 256, 0, stream>>>(qkvB, VtG);

    attn_mfma6<<<dim3(768), 256, 0, stream>>>(qkvB, VtG, xYb);

    gemm_mfma<0, 0><<<dim3(CEMB / 128, M / 128), 256, 0, stream>>>(
        xYb, wpT, b_proj, out, M, CEMB, CEMB);
}

// Round 9
// 256.042 us; speedup vs baseline: 1.7840x; 1.5054x over previous
//
#include <hip/hip_runtime.h>

#define TSEQ 4096
#define CEMB 768
#define NHEAD 12

using bf16x8 = __attribute__((ext_vector_type(8))) short;
using f32x4  = __attribute__((ext_vector_type(4))) float;

#if __has_builtin(__builtin_amdgcn_exp2f)
#define EXP2(x) __builtin_amdgcn_exp2f(x)
#else
#define EXP2(x) exp2f(x)
#endif

__device__ __forceinline__ unsigned int f2bf(float f) {
    unsigned int u = __float_as_uint(f);
    return (u + 0x7fffu + ((u >> 16) & 1u)) >> 16;   // RNE
}
__device__ __forceinline__ unsigned int f2bf_fast(float f) {
    return (__float_as_uint(f) + 0x8000u) >> 16;     // ~RNE, <=1ulp diff
}
__device__ __forceinline__ void async_cp16(void* lds, const void* g) {
    __builtin_amdgcn_global_load_lds(
        (const __attribute__((address_space(1))) void*)g,
        (__attribute__((address_space(3))) void*)lds, 16, 0, 0);
}
__device__ __forceinline__ float warp_max16(float v) {
    v = fmaxf(v, __shfl_xor(v, 1));
    v = fmaxf(v, __shfl_xor(v, 2));
    v = fmaxf(v, __shfl_xor(v, 4));
    v = fmaxf(v, __shfl_xor(v, 8));
    return v;
}
__device__ __forceinline__ float warp_sum16(float v) {
    v += __shfl_xor(v, 1);
    v += __shfl_xor(v, 2);
    v += __shfl_xor(v, 4);
    v += __shfl_xor(v, 8);
    return v;
}

// ---------------- x fp32 -> bf16 ----------------
__global__ __launch_bounds__(256) void cvt_bf16(
    const float* __restrict__ X, unsigned short* __restrict__ Xb, int n8)
{
    int i = blockIdx.x * 256 + threadIdx.x;
    if (i >= n8) return;
    float4 a = *reinterpret_cast<const float4*>(&X[(size_t)i * 8]);
    float4 b = *reinterpret_cast<const float4*>(&X[(size_t)i * 8 + 4]);
    uint4 o;
    o.x = f2bf(a.x) | (f2bf(a.y) << 16);
    o.y = f2bf(a.z) | (f2bf(a.w) << 16);
    o.z = f2bf(b.x) | (f2bf(b.y) << 16);
    o.w = f2bf(b.z) | (f2bf(b.w) << 16);
    *reinterpret_cast<uint4*>(&Xb[(size_t)i * 8]) = o;
}

// ---------------- W fp32 [K][N] -> bf16 [N][K] ----------------
__global__ __launch_bounds__(256) void wtrans(
    const float* __restrict__ W, unsigned short* __restrict__ WT, int K, int N)
{
    __shared__ unsigned short tile[64][72];
    const int k0 = blockIdx.y * 64, n0 = blockIdx.x * 64;
    const int tid = threadIdx.x;
#pragma unroll
    for (int it = 0; it < 4; ++it) {
        int f = tid + it * 256;
        int r = f >> 4, c4 = f & 15;
        float4 v = *reinterpret_cast<const float4*>(&W[(size_t)(k0 + r) * N + n0 + c4 * 4]);
        tile[r][c4 * 4 + 0] = (unsigned short)f2bf(v.x);
        tile[r][c4 * 4 + 1] = (unsigned short)f2bf(v.y);
        tile[r][c4 * 4 + 2] = (unsigned short)f2bf(v.z);
        tile[r][c4 * 4 + 3] = (unsigned short)f2bf(v.w);
    }
    __syncthreads();
#pragma unroll
    for (int it = 0; it < 2; ++it) {
        int f = tid + it * 256;
        int rn = f >> 3, c8 = f & 7;
        unsigned short tmp[8];
#pragma unroll
        for (int j = 0; j < 8; ++j) tmp[j] = tile[c8 * 8 + j][rn];
        *reinterpret_cast<uint4*>(&WT[(size_t)(n0 + rn) * K + k0 + c8 * 8]) =
            *reinterpret_cast<uint4*>(tmp);
    }
}

// ---------------- bf16 MFMA GEMM: C[m][n] = A[m][k] * BT[n][k] + bias ----------------
template<int BF16OUT, int QSCALE>
__global__ __launch_bounds__(256) void gemm_mfma(
    const unsigned short* __restrict__ A,
    const unsigned short* __restrict__ BT,
    const float* __restrict__ bias,
    void* __restrict__ Cv,
    int M, int N, int K)
{
    __shared__ __align__(16) unsigned short As[128 * 64];
    __shared__ __align__(16) unsigned short Bs[128 * 64];

    const int nwg = gridDim.x * gridDim.y;
    const int id = blockIdx.y * gridDim.x + blockIdx.x;
    const int qx = nwg >> 3;
    const int swz = (id & 7) * qx + (id >> 3);
    const int nb = N >> 7;
    const int m0 = (swz / nb) * 128, n0 = (swz % nb) * 128;

    const int tid = threadIdx.x;
    const int w = tid >> 6, lane = tid & 63;
    const int wr = w >> 1, wc = w & 1;
    const int lq = lane & 15, g = lane >> 4;
    const int wrOff = wr * 64, wcOff = wc * 64;

    f32x4 acc[4][4];
#pragma unroll
    for (int i = 0; i < 4; ++i)
#pragma unroll
        for (int j = 0; j < 4; ++j) acc[i][j] = (f32x4){0.f, 0.f, 0.f, 0.f};

    for (int k0 = 0; k0 < K; k0 += 64) {
#pragma unroll
        for (int it = 0; it < 4; ++it) {
            const int dbase = it * 256 + w * 64;
            const int d = dbase + lane;
            const int r = d >> 3;
            const int s = (d & 7) ^ (r & 7);
            async_cp16((char*)As + dbase * 16, A + (size_t)(m0 + r) * K + k0 + s * 8);
            async_cp16((char*)Bs + dbase * 16, BT + (size_t)(n0 + r) * K + k0 + s * 8);
        }
        __syncthreads();

#pragma unroll
        for (int kk = 0; kk < 2; ++kk) {
            bf16x8 af[4], bfr[4];
#pragma unroll
            for (int i = 0; i < 4; ++i) {
                const int ra = wrOff + i * 16 + lq;
                af[i] = *reinterpret_cast<const bf16x8*>(
                    (char*)As + ra * 128 + (((kk * 4 + g) ^ (ra & 7)) << 4));
                const int rb = wcOff + i * 16 + lq;
                bfr[i] = *reinterpret_cast<const bf16x8*>(
                    (char*)Bs + rb * 128 + (((kk * 4 + g) ^ (rb & 7)) << 4));
            }
#pragma unroll
            for (int i = 0; i < 4; ++i)
#pragma unroll
                for (int j = 0; j < 4; ++j)
                    acc[i][j] = __builtin_amdgcn_mfma_f32_16x16x32_bf16(
                        af[i], bfr[j], acc[i][j], 0, 0, 0);
        }
        __syncthreads();
    }

#pragma unroll
    for (int i = 0; i < 4; ++i)
#pragma unroll
        for (int j = 0; j < 4; ++j) {
            const int col = n0 + wcOff + j * 16 + lq;
            const float bv = bias[col];
            // q gets 1/8 (attn scale) * log2(e) (exp2-domain softmax) folded in
            const float scl = (QSCALE && col < CEMB) ? 0.18033688011112042f : 1.0f;
#pragma unroll
            for (int rg = 0; rg < 4; ++rg) {
                const int row = m0 + wrOff + i * 16 + g * 4 + rg;
                const float v = (acc[i][j][rg] + bv) * scl;
                if (BF16OUT)
                    ((unsigned short*)Cv)[(size_t)row * N + col] = (unsigned short)f2bf(v);
                else
                    ((float*)Cv)[(size_t)row * N + col] = v;
            }
        }
}

// ---------------- V transpose: qkv bf16 v-slice -> Vt [bh][64 d][4096 t] ----------------
__global__ __launch_bounds__(256) void vtrans(
    const unsigned short* __restrict__ qkvB, unsigned short* __restrict__ VtG)
{
    __shared__ unsigned short tile[64][66];
    const int t0 = blockIdx.x * 64;
    const int bh = blockIdx.y;
    const int b = bh / NHEAD, h = bh % NHEAD;
    const size_t rowBase = (size_t)b * TSEQ;
    const int tid = threadIdx.x;

#pragma unroll
    for (int it = 0; it < 2; ++it) {
        int f = tid + 256 * it;
        int r = f >> 3, s = f & 7;
        unsigned short tmp[8];
        *reinterpret_cast<uint4*>(tmp) = *reinterpret_cast<const uint4*>(
            &qkvB[(rowBase + t0 + r) * 2304 + 2 * CEMB + h * 64 + s * 8]);
#pragma unroll
        for (int j = 0; j < 8; ++j) tile[r][s * 8 + j] = tmp[j];
    }
    __syncthreads();
#pragma unroll
    for (int it = 0; it < 2; ++it) {
        int f = tid + 256 * it;
        int d = f >> 3, c = f & 7;
        unsigned short tmp[8];
#pragma unroll
        for (int j = 0; j < 8; ++j) tmp[j] = tile[c * 8 + j][d];
        *reinterpret_cast<uint4*>(&VtG[(size_t)bh * 64 * TSEQ + (size_t)d * TSEQ + t0 + c * 8]) =
            *reinterpret_cast<uint4*>(tmp);
    }
}

// ---- per-tile pieces (layouts identical to the numerically-verified r3/r6 kernel) ----
#define QK_TILE(SFR, QF)                                                              \
{                                                                                     \
    _Pragma("unroll")                                                                 \
    for (int c = 0; c < 4; ++c) {                                                     \
        const int kvr = 16 * c + lq;                                                  \
        const int xr = lq & 7;                                                        \
        bf16x8 k0 = *reinterpret_cast<const bf16x8*>(Kb + kvr * 128 + ((g ^ xr) << 4));       \
        bf16x8 k1 = *reinterpret_cast<const bf16x8*>(Kb + kvr * 128 + (((4 + g) ^ xr) << 4)); \
        f32x4 a0 = (f32x4){0.f, 0.f, 0.f, 0.f};                                       \
        a0 = __builtin_amdgcn_mfma_f32_16x16x32_bf16(QF[0], k0, a0, 0, 0, 0);         \
        a0 = __builtin_amdgcn_mfma_f32_16x16x32_bf16(QF[1], k1, a0, 0, 0, 0);         \
        SFR[c] = a0;                                                                  \
    }                                                                                 \
}

#define MASK_TILE(SFR)                                                                \
{                                                                                     \
    const int qp = 16 * w + 4 * g;                                                    \
    _Pragma("unroll")                                                                 \
    for (int c = 0; c < 4; ++c) {                                                     \
        const int kp = 16 * c + lq;                                                   \
        _Pragma("unroll")                                                             \
        for (int r = 0; r < 4; ++r)                                                   \
            if (kp > qp + r) SFR[c][r] = -1e30f;                                      \
    }                                                                                 \
}

// branchless online softmax (r6-verified form; defer-rescale removed — its branch
// fenced the dual-chain interleave and cost 1.7x in r8)
#define SM_TILE(SFR, MM, LL, OO)                                                      \
{                                                                                     \
    _Pragma("unroll")                                                                 \
    for (int r = 0; r < 4; ++r) {                                                     \
        float mx = fmaxf(fmaxf(SFR[0][r], SFR[1][r]), fmaxf(SFR[2][r], SFR[3][r]));   \
        mx = warp_max16(mx);                                                          \
        const float mnew = fmaxf(MM[r], mx);                                          \
        const float al = EXP2(MM[r] - mnew);                                          \
        float rs = 0.f;                                                               \
        _Pragma("unroll")                                                             \
        for (int c = 0; c < 4; ++c) {                                                 \
            const float p = EXP2(SFR[c][r] - mnew);                                   \
            SFR[c][r] = p;                                                            \
            rs += p;                                                                  \
        }                                                                             \
        rs = warp_sum16(rs);                                                          \
        LL[r] = al * LL[r] + rs;                                                      \
        MM[r] = mnew;                                                                 \
        _Pragma("unroll")                                                             \
        for (int dt = 0; dt < 4; ++dt) OO[dt][r] *= al;                               \
    }                                                                                 \
}

#define PW_TILE(SFR, PWP)                                                             \
{                                                                                     \
    _Pragma("unroll")                                                                 \
    for (int c = 0; c < 4; ++c) {                                                     \
        const int kp = 16 * c + lq;                                                   \
        _Pragma("unroll")                                                             \
        for (int r = 0; r < 4; ++r) {                                                 \
            const int qp = 4 * g + r;                                                 \
            const int byt = qp * 128 + (((kp >> 3) ^ (qp & 7)) << 4) + (kp & 7) * 2;  \
            *reinterpret_cast<unsigned short*>(PWP + byt) =                           \
                (unsigned short)f2bf_fast(SFR[c][r]);                                 \
        }                                                                             \
    }                                                                                 \
}

#define PV_TILE(OO, PWP)                                                              \
{                                                                                     \
    _Pragma("unroll")                                                                 \
    for (int ktile = 0; ktile < 2; ++ktile) {                                         \
        bf16x8 pf = *reinterpret_cast<const bf16x8*>(                                 \
            PWP + lq * 128 + (((4 * ktile + g) ^ (lq & 7)) << 4));                    \
        _Pragma("unroll")                                                             \
        for (int dt = 0; dt < 4; ++dt) {                                              \
            const int d = 16 * dt + lq;                                               \
            bf16x8 vf = *reinterpret_cast<const bf16x8*>(                             \
                Vb + d * 128 + (((4 * ktile + g) ^ (d & 7)) << 4));                   \
            OO[dt] = __builtin_amdgcn_mfma_f32_16x16x32_bf16(pf, vf, OO[dt], 0, 0, 0);\
        }                                                                             \
    }                                                                                 \
}

#define STAGE_KV(KT, BUF)                                                             \
{                                                                                     \
    const int kn = (KT) * 64;                                                         \
    _Pragma("unroll")                                                                 \
    for (int it = 0; it < 2; ++it) {                                                  \
        const int dbase = it * 256 + w * 64;                                          \
        const int d = dbase + lane;                                                   \
        const int r = d >> 3;                                                         \
        const int s = (d & 7) ^ (r & 7);                                              \
        async_cp16(Kl[BUF] + dbase * 16, qkvB + (rowBase + kn + r) * 2304 + kOff + s * 8); \
        async_cp16(Vl[BUF] + dbase * 16, Vhead + (size_t)r * TSEQ + kn + s * 8);      \
    }                                                                                 \
}

// ---------------- MFMA flash attention v7: r6 compute + XCD-bijective bh mapping ----------------
// 1-D grid 768. XCD k (= id&7) owns bh = 3k + (local%3); qtA = local/3 pairs with 63-qtA.
__global__ __launch_bounds__(256, 3) void attn_mfma7(
    const unsigned short* __restrict__ qkvB,   // bf16 [8192][2304], q pre-scaled 0.125*log2e
    const unsigned short* __restrict__ VtG,    // bf16 [24][64][4096]
    unsigned short* __restrict__ Yb)           // bf16 [8192][768]
{
    __shared__ __align__(16) char Kl[2][8192];   // [kv 64][d 64], 16B-chunk XOR swizzle
    __shared__ __align__(16) char Vl[2][8192];   // [d 64][kv 64], swizzled
    __shared__ __align__(16) char PlA[8192];     // 4 waves x [q 16][kv 64], swizzled
    __shared__ __align__(16) char PlB[8192];

    const int NT = TSEQ / 64;
    const int id = blockIdx.x;                   // 0..767
    const int xcd = id & 7;
    const int local = id >> 3;                   // 0..95
    const int bh = xcd * 3 + (local % 3);        // 3 bh per XCD -> K/V L2-resident
    const int qtA = local / 3;                   // 0..31
    const int qtB = NT - 1 - qtA;                // 63..32

    const int b = bh / NHEAD, h = bh % NHEAD;
    const int tid = threadIdx.x;
    const int w = tid >> 6, lane = tid & 63;
    const int g = lane >> 4, lq = lane & 15;

    const size_t rowBase = (size_t)b * TSEQ;
    const int kOff = CEMB + h * 64;
    const unsigned short* Vhead = VtG + (size_t)bh * 64 * TSEQ;

    bf16x8 qfA[2], qfB[2];
    {
        const size_t rA = rowBase + (size_t)qtA * 64 + 16 * w + lq;
        const size_t rB = rowBase + (size_t)qtB * 64 + 16 * w + lq;
#pragma unroll
        for (int dt = 0; dt < 2; ++dt) {
            qfA[dt] = *reinterpret_cast<const bf16x8*>(&qkvB[rA * 2304 + h * 64 + 32 * dt + 8 * g]);
            qfB[dt] = *reinterpret_cast<const bf16x8*>(&qkvB[rB * 2304 + h * 64 + 32 * dt + 8 * g]);
        }
    }

    f32x4 oA[4], oB[4];
    float mA[4], lA[4], mB[4], lB[4];
#pragma unroll
    for (int r = 0; r < 4; ++r) {
        mA[r] = -1e30f; lA[r] = 0.f; mB[r] = -1e30f; lB[r] = 0.f;
    }
#pragma unroll
    for (int dt = 0; dt < 4; ++dt) {
        oA[dt] = (f32x4){0.f, 0.f, 0.f, 0.f};
        oB[dt] = (f32x4){0.f, 0.f, 0.f, 0.f};
    }

    char* PwA = PlA + w * 2048;
    char* PwB = PlB + w * 2048;

    STAGE_KV(0, 0);

    // ---- phase 1: kt = 0..qtA — both tiles active, staggered dual chains ----
    for (int kt = 0; kt <= qtA; ++kt) {
        const int cur = kt & 1;
        __syncthreads();
        STAGE_KV(kt + 1, cur ^ 1);           // kt+1 <= qtA+1 <= qtB, always valid
        const char* Kb = Kl[cur];
        const char* Vb = Vl[cur];

        f32x4 sfrA[4], sfrB[4];
        QK_TILE(sfrA, qfA);
        QK_TILE(sfrB, qfB);
        if (kt == qtA) MASK_TILE(sfrA);
        SM_TILE(sfrA, mA, lA, oA);
        SM_TILE(sfrB, mB, lB, oB);
        PW_TILE(sfrA, PwA);
        PW_TILE(sfrB, PwB);
        PV_TILE(oA, PwA);
        PV_TILE(oB, PwB);
    }

    // ---- phase 2: kt = qtA+1..qtB — only tile B ----
    for (int kt = qtA + 1; kt <= qtB; ++kt) {
        const int cur = kt & 1;
        __syncthreads();
        if (kt < qtB) STAGE_KV(kt + 1, cur ^ 1);
        const char* Kb = Kl[cur];
        const char* Vb = Vl[cur];

        f32x4 sfrB[4];
        QK_TILE(sfrB, qfB);
        if (kt == qtB) MASK_TILE(sfrB);
        SM_TILE(sfrB, mB, lB, oB);
        PW_TILE(sfrB, PwB);
        PV_TILE(oB, PwB);
    }

    // ---- outputs ----
#pragma unroll
    for (int r = 0; r < 4; ++r) {
        const float invA = 1.f / lA[r];
        const float invB = 1.f / lB[r];
        const size_t rowA = rowBase + (size_t)qtA * 64 + 16 * w + 4 * g + r;
        const size_t rowB = rowBase + (size_t)qtB * 64 + 16 * w + 4 * g + r;
#pragma unroll
        for (int dt = 0; dt < 4; ++dt) {
            Yb[rowA * CEMB + h * 64 + 16 * dt + lq] = (unsigned short)f2bf_fast(oA[dt][r] * invA);
            Yb[rowB * CEMB + h * 64 + 16 * dt + lq] = (unsigned short)f2bf_fast(oB[dt][r] * invB);
        }
    }
}

extern "C" void kernel_launch(void* const* d_in, const int* in_sizes, int n_in,
                              void* d_out, int out_size, void* d_ws, size_t ws_size,
                              hipStream_t stream)
{
    const float* x      = (const float*)d_in[0];
    const float* w_attn = (const float*)d_in[1];
    const float* b_attn = (const float*)d_in[2];
    const float* w_proj = (const float*)d_in[3];
    const float* b_proj = (const float*)d_in[4];
    float* out = (float*)d_out;

    const int M = 2 * TSEQ;  // 8192
    char* ws = (char*)d_ws;
    unsigned short* qkvB = (unsigned short*)ws;                   // 37,748,736 B
    unsigned short* VtG  = (unsigned short*)(ws + 37748736);      // 12,582,912 B
    unsigned short* xYb  = (unsigned short*)(ws + 50331648);      // 12,582,912 B (xB, then Yb)
    unsigned short* wT   = (unsigned short*)(ws + 62914560);      //  3,538,944 B
    unsigned short* wpT  = (unsigned short*)(ws + 66453504);      //  1,179,648 B

    cvt_bf16<<<dim3((M * CEMB) / 8 / 256), 256, 0, stream>>>(x, xYb, (M * CEMB) / 8);
    wtrans<<<dim3(3 * CEMB / 64, CEMB / 64), 256, 0, stream>>>(w_attn, wT, CEMB, 3 * CEMB);
    wtrans<<<dim3(CEMB / 64, CEMB / 64), 256, 0, stream>>>(w_proj, wpT, CEMB, CEMB);

    gemm_mfma<1, 1><<<dim3(3 * CEMB / 128, M / 128), 256, 0, stream>>>(
        xYb, wT, b_attn, qkvB, M, 3 * CEMB, CEMB);

    vtrans<<<dim3(TSEQ / 64, 2 * NHEAD), 256, 0, stream>>>(qkvB, VtG);

    attn_mfma7<<<dim3(768), 256, 0, stream>>>(qkvB, VtG, xYb);

    gemm_mfma<0, 0><<<dim3(CEMB / 128, M / 128), 256, 0, stream>>>(
        xYb, wpT, b_proj, out, M, CEMB, CEMB);
}

// Round 10
// 183.524 us; speedup vs baseline: 2.4889x; 1.3951x over previous
//
#include <hip/hip_runtime.h>

#define TSEQ 4096
#define CEMB 768
#define NHEAD 12

using bf16x8 = __attribute__((ext_vector_type(8))) short;
using f32x4  = __attribute__((ext_vector_type(4))) float;

#if __has_builtin(__builtin_amdgcn_exp2f)
#define EXP2(x) __builtin_amdgcn_exp2f(x)
#else
#define EXP2(x) exp2f(x)
#endif

__device__ __forceinline__ unsigned int f2bf(float f) {
    unsigned int u = __float_as_uint(f);
    return (u + 0x7fffu + ((u >> 16) & 1u)) >> 16;   // RNE
}
__device__ __forceinline__ unsigned int f2bf_fast(float f) {
    return (__float_as_uint(f) + 0x8000u) >> 16;     // ~RNE, <=1ulp diff
}
__device__ __forceinline__ unsigned int cvt_pk_bf16(float lo, float hi) {
    unsigned int r;
    asm("v_cvt_pk_bf16_f32 %0, %1, %2" : "=v"(r) : "v"(lo), "v"(hi));
    return r;
}
__device__ __forceinline__ void async_cp16(void* lds, const void* g) {
    __builtin_amdgcn_global_load_lds(
        (const __attribute__((address_space(1))) void*)g,
        (__attribute__((address_space(3))) void*)lds, 16, 0, 0);
}

// ---------------- x fp32 -> bf16 ----------------
__global__ __launch_bounds__(256) void cvt_bf16(
    const float* __restrict__ X, unsigned short* __restrict__ Xb, int n8)
{
    int i = blockIdx.x * 256 + threadIdx.x;
    if (i >= n8) return;
    float4 a = *reinterpret_cast<const float4*>(&X[(size_t)i * 8]);
    float4 b = *reinterpret_cast<const float4*>(&X[(size_t)i * 8 + 4]);
    uint4 o;
    o.x = f2bf(a.x) | (f2bf(a.y) << 16);
    o.y = f2bf(a.z) | (f2bf(a.w) << 16);
    o.z = f2bf(b.x) | (f2bf(b.y) << 16);
    o.w = f2bf(b.z) | (f2bf(b.w) << 16);
    *reinterpret_cast<uint4*>(&Xb[(size_t)i * 8]) = o;
}

// ---------------- W fp32 [K][N] -> bf16 [N][K] ----------------
__global__ __launch_bounds__(256) void wtrans(
    const float* __restrict__ W, unsigned short* __restrict__ WT, int K, int N)
{
    __shared__ unsigned short tile[64][72];
    const int k0 = blockIdx.y * 64, n0 = blockIdx.x * 64;
    const int tid = threadIdx.x;
#pragma unroll
    for (int it = 0; it < 4; ++it) {
        int f = tid + it * 256;
        int r = f >> 4, c4 = f & 15;
        float4 v = *reinterpret_cast<const float4*>(&W[(size_t)(k0 + r) * N + n0 + c4 * 4]);
        tile[r][c4 * 4 + 0] = (unsigned short)f2bf(v.x);
        tile[r][c4 * 4 + 1] = (unsigned short)f2bf(v.y);
        tile[r][c4 * 4 + 2] = (unsigned short)f2bf(v.z);
        tile[r][c4 * 4 + 3] = (unsigned short)f2bf(v.w);
    }
    __syncthreads();
#pragma unroll
    for (int it = 0; it < 2; ++it) {
        int f = tid + it * 256;
        int rn = f >> 3, c8 = f & 7;
        unsigned short tmp[8];
#pragma unroll
        for (int j = 0; j < 8; ++j) tmp[j] = tile[c8 * 8 + j][rn];
        *reinterpret_cast<uint4*>(&WT[(size_t)(n0 + rn) * K + k0 + c8 * 8]) =
            *reinterpret_cast<uint4*>(tmp);
    }
}

// ---------------- bf16 MFMA GEMM: C[m][n] = A[m][k] * BT[n][k] + bias ----------------
template<int BF16OUT, int QSCALE>
__global__ __launch_bounds__(256) void gemm_mfma(
    const unsigned short* __restrict__ A,
    const unsigned short* __restrict__ BT,
    const float* __restrict__ bias,
    void* __restrict__ Cv,
    int M, int N, int K)
{
    __shared__ __align__(16) unsigned short As[128 * 64];
    __shared__ __align__(16) unsigned short Bs[128 * 64];

    const int nwg = gridDim.x * gridDim.y;
    const int id = blockIdx.y * gridDim.x + blockIdx.x;
    const int qx = nwg >> 3;
    const int swz = (id & 7) * qx + (id >> 3);
    const int nb = N >> 7;
    const int m0 = (swz / nb) * 128, n0 = (swz % nb) * 128;

    const int tid = threadIdx.x;
    const int w = tid >> 6, lane = tid & 63;
    const int wr = w >> 1, wc = w & 1;
    const int lq = lane & 15, g = lane >> 4;
    const int wrOff = wr * 64, wcOff = wc * 64;

    f32x4 acc[4][4];
#pragma unroll
    for (int i = 0; i < 4; ++i)
#pragma unroll
        for (int j = 0; j < 4; ++j) acc[i][j] = (f32x4){0.f, 0.f, 0.f, 0.f};

    for (int k0 = 0; k0 < K; k0 += 64) {
#pragma unroll
        for (int it = 0; it < 4; ++it) {
            const int dbase = it * 256 + w * 64;
            const int d = dbase + lane;
            const int r = d >> 3;
            const int s = (d & 7) ^ (r & 7);
            async_cp16((char*)As + dbase * 16, A + (size_t)(m0 + r) * K + k0 + s * 8);
            async_cp16((char*)Bs + dbase * 16, BT + (size_t)(n0 + r) * K + k0 + s * 8);
        }
        __syncthreads();

#pragma unroll
        for (int kk = 0; kk < 2; ++kk) {
            bf16x8 af[4], bfr[4];
#pragma unroll
            for (int i = 0; i < 4; ++i) {
                const int ra = wrOff + i * 16 + lq;
                af[i] = *reinterpret_cast<const bf16x8*>(
                    (char*)As + ra * 128 + (((kk * 4 + g) ^ (ra & 7)) << 4));
                const int rb = wcOff + i * 16 + lq;
                bfr[i] = *reinterpret_cast<const bf16x8*>(
                    (char*)Bs + rb * 128 + (((kk * 4 + g) ^ (rb & 7)) << 4));
            }
#pragma unroll
            for (int i = 0; i < 4; ++i)
#pragma unroll
                for (int j = 0; j < 4; ++j)
                    acc[i][j] = __builtin_amdgcn_mfma_f32_16x16x32_bf16(
                        af[i], bfr[j], acc[i][j], 0, 0, 0);
        }
        __syncthreads();
    }

#pragma unroll
    for (int i = 0; i < 4; ++i)
#pragma unroll
        for (int j = 0; j < 4; ++j) {
            const int col = n0 + wcOff + j * 16 + lq;
            const float bv = bias[col];
            // q gets 1/8 (attn scale) * log2(e) (exp2-domain softmax) folded in
            const float scl = (QSCALE && col < CEMB) ? 0.18033688011112042f : 1.0f;
#pragma unroll
            for (int rg = 0; rg < 4; ++rg) {
                const int row = m0 + wrOff + i * 16 + g * 4 + rg;
                const float v = (acc[i][j][rg] + bv) * scl;
                if (BF16OUT)
                    ((unsigned short*)Cv)[(size_t)row * N + col] = (unsigned short)f2bf(v);
                else
                    ((float*)Cv)[(size_t)row * N + col] = v;
            }
        }
}

// ---------------- V transpose: qkv bf16 v-slice -> Vt [bh][64 d][4096 t] ----------------
__global__ __launch_bounds__(256) void vtrans(
    const unsigned short* __restrict__ qkvB, unsigned short* __restrict__ VtG)
{
    __shared__ unsigned short tile[64][66];
    const int t0 = blockIdx.x * 64;
    const int bh = blockIdx.y;
    const int b = bh / NHEAD, h = bh % NHEAD;
    const size_t rowBase = (size_t)b * TSEQ;
    const int tid = threadIdx.x;

#pragma unroll
    for (int it = 0; it < 2; ++it) {
        int f = tid + 256 * it;
        int r = f >> 3, s = f & 7;
        unsigned short tmp[8];
        *reinterpret_cast<uint4*>(tmp) = *reinterpret_cast<const uint4*>(
            &qkvB[(rowBase + t0 + r) * 2304 + 2 * CEMB + h * 64 + s * 8]);
#pragma unroll
        for (int j = 0; j < 8; ++j) tile[r][s * 8 + j] = tmp[j];
    }
    __syncthreads();
#pragma unroll
    for (int it = 0; it < 2; ++it) {
        int f = tid + 256 * it;
        int d = f >> 3, c = f & 7;
        unsigned short tmp[8];
#pragma unroll
        for (int j = 0; j < 8; ++j) tmp[j] = tile[c * 8 + j][d];
        *reinterpret_cast<uint4*>(&VtG[(size_t)bh * 64 * TSEQ + (size_t)d * TSEQ + t0 + c * 8]) =
            *reinterpret_cast<uint4*>(tmp);
    }
}

// ==== swapped-operand attention pieces (fragment mappings verified by the passing r4 run) ====
// S layout: SFR[c][r] = S[kv = 16c+4g+r][q = lq]  (from mfma(K, Q))

// dual-chain QK^T with shared K-fragment reads
#define QK_DUAL(SA, SB)                                                               \
{                                                                                     \
    const int xr = lq & 7;                                                            \
    _Pragma("unroll")                                                                 \
    for (int c = 0; c < 4; ++c) {                                                     \
        const int krow = 16 * c + lq;                                                 \
        bf16x8 kf0 = *reinterpret_cast<const bf16x8*>(Kb + krow * 128 + ((g ^ xr) << 4));       \
        bf16x8 kf1 = *reinterpret_cast<const bf16x8*>(Kb + krow * 128 + (((4 + g) ^ xr) << 4)); \
        f32x4 a = (f32x4){0.f, 0.f, 0.f, 0.f};                                        \
        a = __builtin_amdgcn_mfma_f32_16x16x32_bf16(kf0, qfA[0], a, 0, 0, 0);         \
        a = __builtin_amdgcn_mfma_f32_16x16x32_bf16(kf1, qfA[1], a, 0, 0, 0);         \
        SA[c] = a;                                                                    \
        f32x4 bb = (f32x4){0.f, 0.f, 0.f, 0.f};                                       \
        bb = __builtin_amdgcn_mfma_f32_16x16x32_bf16(kf0, qfB[0], bb, 0, 0, 0);       \
        bb = __builtin_amdgcn_mfma_f32_16x16x32_bf16(kf1, qfB[1], bb, 0, 0, 0);       \
        SB[c] = bb;                                                                   \
    }                                                                                 \
}

#define QK_ONE(SB, QF)                                                                \
{                                                                                     \
    const int xr = lq & 7;                                                            \
    _Pragma("unroll")                                                                 \
    for (int c = 0; c < 4; ++c) {                                                     \
        const int krow = 16 * c + lq;                                                 \
        bf16x8 kf0 = *reinterpret_cast<const bf16x8*>(Kb + krow * 128 + ((g ^ xr) << 4));       \
        bf16x8 kf1 = *reinterpret_cast<const bf16x8*>(Kb + krow * 128 + (((4 + g) ^ xr) << 4)); \
        f32x4 a = (f32x4){0.f, 0.f, 0.f, 0.f};                                        \
        a = __builtin_amdgcn_mfma_f32_16x16x32_bf16(kf0, QF[0], a, 0, 0, 0);          \
        a = __builtin_amdgcn_mfma_f32_16x16x32_bf16(kf1, QF[1], a, 0, 0, 0);          \
        SB[c] = a;                                                                    \
    }                                                                                 \
}

// causal mask on diagonal tile: kv = 16c+4g+r (tile-local), q = 16w+lq (tile-local)
#define MASK_TILE(SFR)                                                                \
{                                                                                     \
    const int qloc = 16 * w + lq;                                                     \
    _Pragma("unroll")                                                                 \
    for (int c = 0; c < 4; ++c)                                                       \
        _Pragma("unroll")                                                             \
        for (int r = 0; r < 4; ++r)                                                   \
            if (16 * c + 4 * g + r > qloc) SFR[c][r] = -1e30f;                        \
}

// branchless online softmax, q lane-local: in-lane tree + 2 shuffles per reduction
#define SM_TILE(SFR, MM, LL, OO)                                                      \
{                                                                                     \
    float mx = SFR[0][0];                                                             \
    _Pragma("unroll")                                                                 \
    for (int c = 0; c < 4; ++c)                                                       \
        _Pragma("unroll")                                                             \
        for (int r = 0; r < 4; ++r) mx = fmaxf(mx, SFR[c][r]);                        \
    mx = fmaxf(mx, __shfl_xor(mx, 16));                                               \
    mx = fmaxf(mx, __shfl_xor(mx, 32));                                               \
    const float mnew = fmaxf(MM, mx);                                                 \
    const float al = EXP2(MM - mnew);                                                 \
    MM = mnew;                                                                        \
    float rs = 0.f;                                                                   \
    _Pragma("unroll")                                                                 \
    for (int c = 0; c < 4; ++c)                                                       \
        _Pragma("unroll")                                                             \
        for (int r = 0; r < 4; ++r) {                                                 \
            const float p = EXP2(SFR[c][r] - mnew);                                   \
            SFR[c][r] = p;                                                            \
            rs += p;                                                                  \
        }                                                                             \
    rs += __shfl_xor(rs, 16);                                                         \
    rs += __shfl_xor(rs, 32);                                                         \
    LL = al * LL + rs;                                                                \
    _Pragma("unroll")                                                                 \
    for (int dt = 0; dt < 4; ++dt) OO[dt] *= al;                                      \
}

// P -> per-wave LDS [q 16][kv 64] bf16, 16B-chunk XOR swizzle; 4x ds_write_b64
#define PW_TILE(SFR, PWP)                                                             \
{                                                                                     \
    _Pragma("unroll")                                                                 \
    for (int c = 0; c < 4; ++c) {                                                     \
        uint2 pk;                                                                     \
        pk.x = cvt_pk_bf16(SFR[c][0], SFR[c][1]);                                     \
        pk.y = cvt_pk_bf16(SFR[c][2], SFR[c][3]);                                     \
        *reinterpret_cast<uint2*>(PWP + lq * 128 +                                    \
            (((2 * c + (g >> 1)) ^ (lq & 7)) << 4) + (g & 1) * 8) = pk;               \
    }                                                                                 \
}

// dual-chain PV with shared V-fragment reads; full K=32 MFMAs
#define PV_DUAL(OA, OB, PWA, PWB)                                                     \
{                                                                                     \
    const int xq = lq & 7;                                                            \
    bf16x8 pA0 = *reinterpret_cast<const bf16x8*>(PWA + lq * 128 + ((g ^ xq) << 4));       \
    bf16x8 pA1 = *reinterpret_cast<const bf16x8*>(PWA + lq * 128 + (((4 + g) ^ xq) << 4)); \
    bf16x8 pB0 = *reinterpret_cast<const bf16x8*>(PWB + lq * 128 + ((g ^ xq) << 4));       \
    bf16x8 pB1 = *reinterpret_cast<const bf16x8*>(PWB + lq * 128 + (((4 + g) ^ xq) << 4)); \
    _Pragma("unroll")                                                                 \
    for (int dt = 0; dt < 4; ++dt) {                                                  \
        const int vrow = 16 * dt + lq;                                                \
        bf16x8 vf0 = *reinterpret_cast<const bf16x8*>(Vb + vrow * 128 + ((g ^ xq) << 4));       \
        bf16x8 vf1 = *reinterpret_cast<const bf16x8*>(Vb + vrow * 128 + (((4 + g) ^ xq) << 4)); \
        OA[dt] = __builtin_amdgcn_mfma_f32_16x16x32_bf16(vf0, pA0, OA[dt], 0, 0, 0);  \
        OA[dt] = __builtin_amdgcn_mfma_f32_16x16x32_bf16(vf1, pA1, OA[dt], 0, 0, 0);  \
        OB[dt] = __builtin_amdgcn_mfma_f32_16x16x32_bf16(vf0, pB0, OB[dt], 0, 0, 0);  \
        OB[dt] = __builtin_amdgcn_mfma_f32_16x16x32_bf16(vf1, pB1, OB[dt], 0, 0, 0);  \
    }                                                                                 \
}

#define PV_ONE(OB, PWB)                                                               \
{                                                                                     \
    const int xq = lq & 7;                                                            \
    bf16x8 pB0 = *reinterpret_cast<const bf16x8*>(PWB + lq * 128 + ((g ^ xq) << 4));       \
    bf16x8 pB1 = *reinterpret_cast<const bf16x8*>(PWB + lq * 128 + (((4 + g) ^ xq) << 4)); \
    _Pragma("unroll")                                                                 \
    for (int dt = 0; dt < 4; ++dt) {                                                  \
        const int vrow = 16 * dt + lq;                                                \
        bf16x8 vf0 = *reinterpret_cast<const bf16x8*>(Vb + vrow * 128 + ((g ^ xq) << 4));       \
        bf16x8 vf1 = *reinterpret_cast<const bf16x8*>(Vb + vrow * 128 + (((4 + g) ^ xq) << 4)); \
        OB[dt] = __builtin_amdgcn_mfma_f32_16x16x32_bf16(vf0, pB0, OB[dt], 0, 0, 0);  \
        OB[dt] = __builtin_amdgcn_mfma_f32_16x16x32_bf16(vf1, pB1, OB[dt], 0, 0, 0);  \
    }                                                                                 \
}

#define STAGE_KV(KT, BUF)                                                             \
{                                                                                     \
    const int kn = (KT) * 64;                                                         \
    _Pragma("unroll")                                                                 \
    for (int it = 0; it < 2; ++it) {                                                  \
        const int dbase = it * 256 + w * 64;                                          \
        const int d = dbase + lane;                                                   \
        const int r = d >> 3;                                                         \
        const int s = (d & 7) ^ (r & 7);                                              \
        async_cp16(Kl[BUF] + dbase * 16, qkvB + (rowBase + kn + r) * 2304 + kOff + s * 8); \
        async_cp16(Vl[BUF] + dbase * 16, Vhead + (size_t)r * TSEQ + kn + s * 8);      \
    }                                                                                 \
}

// ---------------- MFMA flash attention v8: swapped QK^T, lane-local softmax ----------------
// 1-D grid 768. XCD k (= id&7) owns bh = 3k + (local%3); qtA = local/3 pairs with 63-qtA.
__global__ __launch_bounds__(256, 3) void attn_mfma8(
    const unsigned short* __restrict__ qkvB,   // bf16 [8192][2304], q pre-scaled 0.125*log2e
    const unsigned short* __restrict__ VtG,    // bf16 [24][64][4096]
    unsigned short* __restrict__ Yb)           // bf16 [8192][768]
{
    __shared__ __align__(16) char Kl[2][8192];   // [kv 64][d 64], 16B-chunk XOR swizzle
    __shared__ __align__(16) char Vl[2][8192];   // [d 64][kv 64], swizzled
    __shared__ __align__(16) char PlA[8192];     // 4 waves x [q 16][kv 64], swizzled
    __shared__ __align__(16) char PlB[8192];

    const int NT = TSEQ / 64;
    const int id = blockIdx.x;                   // 0..767
    const int xcd = id & 7;
    const int local = id >> 3;                   // 0..95
    const int bh = xcd * 3 + (local % 3);        // 3 bh per XCD -> K/V L2-resident
    const int qtA = local / 3;                   // 0..31
    const int qtB = NT - 1 - qtA;                // 63..32

    const int b = bh / NHEAD, h = bh % NHEAD;
    const int tid = threadIdx.x;
    const int w = tid >> 6, lane = tid & 63;
    const int g = lane >> 4, lq = lane & 15;

    const size_t rowBase = (size_t)b * TSEQ;
    const int kOff = CEMB + h * 64;
    const unsigned short* Vhead = VtG + (size_t)bh * 64 * TSEQ;

    // Q fragments (B-operand): lane holds Q[16w+lq][32dt+8g+j]
    bf16x8 qfA[2], qfB[2];
    {
        const size_t rA = rowBase + (size_t)qtA * 64 + 16 * w + lq;
        const size_t rB = rowBase + (size_t)qtB * 64 + 16 * w + lq;
#pragma unroll
        for (int dt = 0; dt < 2; ++dt) {
            qfA[dt] = *reinterpret_cast<const bf16x8*>(&qkvB[rA * 2304 + h * 64 + 32 * dt + 8 * g]);
            qfB[dt] = *reinterpret_cast<const bf16x8*>(&qkvB[rB * 2304 + h * 64 + 32 * dt + 8 * g]);
        }
    }

    // O^T state: oX[dt][r] = O[d = 16dt+4g+r][q = lq]; m,l scalar per chain (q=lq)
    f32x4 oA[4], oB[4];
    float mA = -1e30f, lA = 0.f, mB = -1e30f, lB = 0.f;
#pragma unroll
    for (int dt = 0; dt < 4; ++dt) {
        oA[dt] = (f32x4){0.f, 0.f, 0.f, 0.f};
        oB[dt] = (f32x4){0.f, 0.f, 0.f, 0.f};
    }

    char* PwA = PlA + w * 2048;
    char* PwB = PlB + w * 2048;

    STAGE_KV(0, 0);

    // ---- phase 1: kt = 0..qtA — both chains active ----
    for (int kt = 0; kt <= qtA; ++kt) {
        const int cur = kt & 1;
        __syncthreads();
        STAGE_KV(kt + 1, cur ^ 1);           // kt+1 <= qtA+1 <= qtB, always valid
        const char* Kb = Kl[cur];
        const char* Vb = Vl[cur];

        f32x4 sA[4], sB[4];
        QK_DUAL(sA, sB);
        if (kt == qtA) MASK_TILE(sA);
        SM_TILE(sA, mA, lA, oA);
        SM_TILE(sB, mB, lB, oB);
        PW_TILE(sA, PwA);
        PW_TILE(sB, PwB);
        PV_DUAL(oA, oB, PwA, PwB);
    }

    // ---- phase 2: kt = qtA+1..qtB — only chain B ----
    for (int kt = qtA + 1; kt <= qtB; ++kt) {
        const int cur = kt & 1;
        __syncthreads();
        if (kt < qtB) STAGE_KV(kt + 1, cur ^ 1);
        const char* Kb = Kl[cur];
        const char* Vb = Vl[cur];

        f32x4 sB[4];
        QK_ONE(sB, qfB);
        if (kt == qtB) MASK_TILE(sB);
        SM_TILE(sB, mB, lB, oB);
        PW_TILE(sB, PwB);
        PV_ONE(oB, PwB);
    }

    // ---- outputs: O^T -> Y rows q = 16w+lq, packed 8B per dt ----
    const float invA = 1.f / lA;
    const float invB = 1.f / lB;
    const size_t rowA = rowBase + (size_t)qtA * 64 + 16 * w + lq;
    const size_t rowB = rowBase + (size_t)qtB * 64 + 16 * w + lq;
#pragma unroll
    for (int dt = 0; dt < 4; ++dt) {
        uint2 a, bb;
        a.x  = f2bf_fast(oA[dt][0] * invA) | (f2bf_fast(oA[dt][1] * invA) << 16);
        a.y  = f2bf_fast(oA[dt][2] * invA) | (f2bf_fast(oA[dt][3] * invA) << 16);
        bb.x = f2bf_fast(oB[dt][0] * invB) | (f2bf_fast(oB[dt][1] * invB) << 16);
        bb.y = f2bf_fast(oB[dt][2] * invB) | (f2bf_fast(oB[dt][3] * invB) << 16);
        *reinterpret_cast<uint2*>(&Yb[rowA * CEMB + h * 64 + 16 * dt + 4 * g]) = a;
        *reinterpret_cast<uint2*>(&Yb[rowB * CEMB + h * 64 + 16 * dt + 4 * g]) = bb;
    }
}

extern "C" void kernel_launch(void* const* d_in, const int* in_sizes, int n_in,
                              void* d_out, int out_size, void* d_ws, size_t ws_size,
                              hipStream_t stream)
{
    const float* x      = (const float*)d_in[0];
    const float* w_attn = (const float*)d_in[1];
    const float* b_attn = (const float*)d_in[2];
    const float* w_proj = (const float*)d_in[3];
    const float* b_proj = (const float*)d_in[4];
    float* out = (float*)d_out;

    const int M = 2 * TSEQ;  // 8192
    char* ws = (char*)d_ws;
    unsigned short* qkvB = (unsigned short*)ws;                   // 37,748,736 B
    unsigned short* VtG  = (unsigned short*)(ws + 37748736);      // 12,582,912 B
    unsigned short* xYb  = (unsigned short*)(ws + 50331648);      // 12,582,912 B (xB, then Yb)
    unsigned short* wT   = (unsigned short*)(ws + 62914560);      //  3,538,944 B
    unsigned short* wpT  = (unsigned short*)(ws + 66453504);      //  1,179,648 B

    cvt_bf16<<<dim3((M * CEMB) / 8 / 256), 256, 0, stream>>>(x, xYb, (M * CEMB) / 8);
    wtrans<<<dim3(3 * CEMB / 64, CEMB / 64), 256, 0, stream>>>(w_attn, wT, CEMB, 3 * CEMB);
    wtrans<<<dim3(CEMB / 64, CEMB / 64), 256, 0, stream>>>(w_proj, wpT, CEMB, CEMB);

    gemm_mfma<1, 1><<<dim3(3 * CEMB / 128, M / 128), 256, 0, stream>>>(
        xYb, wT, b_attn, qkvB, M, 3 * CEMB, CEMB);

    vtrans<<<dim3(TSEQ / 64, 2 * NHEAD), 256, 0, stream>>>(qkvB, VtG);

    attn_mfma8<<<dim3(768), 256, 0, stream>>>(qkvB, VtG, xYb);

    gemm_mfma<0, 0><<<dim3(CEMB / 128, M / 128), 256, 0, stream>>>(
        xYb, wpT, b_proj, out, M, CEMB, CEMB);
}